// Round 7
// baseline (289.561 us; speedup 1.0000x reference)
//
#include <hip/hip_runtime.h>
#include <hip/hip_bf16.h>
#include <stdint.h>

typedef uint16_t u16;
typedef __attribute__((ext_vector_type(4))) float f32x4;
typedef __attribute__((ext_vector_type(16))) float f32x16;
typedef __attribute__((ext_vector_type(8))) short bf16x8;

#define LOG2E 1.4426950408889634f

static __device__ __forceinline__ u16 f2b(float x){
  union { float f; uint32_t u; } a; a.f = x;
  uint32_t r = a.u + 0x7FFFu + ((a.u >> 16) & 1u);
  return (u16)(r >> 16);
}

// pack two f32 -> two bf16 (round-half-up) in 3 VALU: add, add, v_perm_b32
static __device__ __forceinline__ uint32_t pkrhu(float lo, float hi){
  union { float f; uint32_t u; } a, b; a.f = lo; b.f = hi;
  return __builtin_amdgcn_perm(b.u + 0x8000u, a.u + 0x8000u, 0x07060302u);
}

#define GLD16(g, l) __builtin_amdgcn_global_load_lds((const __attribute__((address_space(1))) void*)(g), (__attribute__((address_space(3))) void*)(l), 16, 0, 0)

// ---------------- cast x: fp32 -> bf16 (8 elems/thread) ----------------
__global__ __launch_bounds__(256) void k_cast(const float* __restrict__ in, u16* __restrict__ out, int n8){
  int i = blockIdx.x * 256 + threadIdx.x;
  if (i >= n8) return;
  const f32x4* p = (const f32x4*)(in + (size_t)i * 8);
  f32x4 a = p[0], b = p[1];
  u16 h[8];
#pragma unroll
  for (int j = 0; j < 4; ++j){ h[j] = f2b(a[j]); h[4+j] = f2b(b[j]); }
  *(bf16x8*)(out + (size_t)i * 8) = *(const bf16x8*)h;
}

// ---------------- transpose-cast: W[R][C] fp32 -> Wt[C][R] bf16 ----------------
__global__ void k_tcast(const float* __restrict__ in, u16* __restrict__ out, int R, int C){
  __shared__ float t[32][33];
  int c0 = blockIdx.x * 32, r0 = blockIdx.y * 32;
  int tx = threadIdx.x, ty = threadIdx.y; // 32 x 8
#pragma unroll
  for (int i = 0; i < 32; i += 8) t[ty + i][tx] = in[(size_t)(r0 + ty + i) * C + c0 + tx];
  __syncthreads();
#pragma unroll
  for (int i = 0; i < 32; i += 8) out[(size_t)(c0 + ty + i) * R + r0 + tx] = f2b(t[tx][ty + i]);
}

// ---------------- QKV GEMM: 128x96 tile, grid 32x24 = 768 blocks (3.0/CU) ----------------
__global__ __launch_bounds__(256) void k_gemmqkv(const u16* __restrict__ A, const u16* __restrict__ Bt,
                                                 u16* __restrict__ Qp, u16* __restrict__ Kp, u16* __restrict__ Vtp){
  __shared__ __align__(16) u16 SM[14336];
  u16* Al = SM; u16* Bl = SM + 8192;
  const int tid = threadIdx.x;
  const int w = tid >> 6, l = tid & 63;
  const int m0 = blockIdx.x * 128, n0 = blockIdx.y * 96;
  const int wm = (w >> 1) * 64, wn = (w & 1) * 48;
  const int lg = l >> 4, lr = l & 15;
  f32x4 acc[4][3] = {};
  const u16* asrc = A  + (size_t)(m0 + w*32 + (l >> 3)) * 768 + (l & 7) * 8;
  const u16* bsrc = Bt + (size_t)(n0 + w*24 + (l >> 3)) * 768 + (l & 7) * 8;
  for (int k0 = 0; k0 < 768; k0 += 64){
#pragma unroll
    for (int i = 0; i < 4; ++i)
      GLD16(asrc + (size_t)(i*8)*768 + k0, &Al[(w*32 + i*8) * 64]);
#pragma unroll
    for (int i = 0; i < 3; ++i)
      GLD16(bsrc + (size_t)(i*8)*768 + k0, &Bl[(w*24 + i*8) * 64]);
    __syncthreads();
    bf16x8 af[4][2], bfr[3][2];
#pragma unroll
    for (int mf = 0; mf < 4; ++mf)
#pragma unroll
      for (int ks = 0; ks < 2; ++ks)
        af[mf][ks] = *(const bf16x8*)&Al[(wm + mf*16 + lr) * 64 + ks*32 + lg*8];
#pragma unroll
    for (int nf = 0; nf < 3; ++nf)
#pragma unroll
      for (int ks = 0; ks < 2; ++ks)
        bfr[nf][ks] = *(const bf16x8*)&Bl[(wn + nf*16 + lr) * 64 + ks*32 + lg*8];
#pragma unroll
    for (int ks = 0; ks < 2; ++ks)
#pragma unroll
      for (int mf = 0; mf < 4; ++mf)
#pragma unroll
        for (int nf = 0; nf < 3; ++nf)
          acc[mf][nf] = __builtin_amdgcn_mfma_f32_16x16x32_bf16(af[mf][ks], bfr[nf][ks], acc[mf][nf], 0, 0, 0);
    __syncthreads();
  }

  const int which = n0 / 768;
  const int nl0 = n0 - which * 768;
  if (which < 2){
    u16* dst = (which == 0) ? Qp : Kp;
    const float sc = (which == 0) ? 0.125f * LOG2E : 1.0f;
#pragma unroll
    for (int mf = 0; mf < 4; ++mf)
#pragma unroll
      for (int nf = 0; nf < 3; ++nf)
#pragma unroll
        for (int r = 0; r < 4; ++r){
          int m = m0 + wm + mf*16 + lg*4 + r;
          int n = nl0 + wn + nf*16 + lr;
          int b = m >> 11, row = m & 2047, hh = n >> 6, d = n & 63;
          dst[(size_t)((b*12 + hh)*2048 + row) * 64 + d] = f2b(acc[mf][nf][r] * sc);
        }
  } else {
#pragma unroll
    for (int mf = 0; mf < 4; ++mf)
#pragma unroll
      for (int nf = 0; nf < 3; ++nf)
#pragma unroll
        for (int r = 0; r < 4; ++r){
          int mrow = wm + mf*16 + lg*4 + r;
          int c    = wn + nf*16 + lr;
          SM[c * 128 + mrow] = f2b(acc[mf][nf][r]);
        }
    __syncthreads();
#pragma unroll
    for (int rr = 0; rr < 6; ++rr){
      int c  = rr*16 + (tid >> 4);
      int mo = (tid & 15) * 8;
      bf16x8 v = *(const bf16x8*)&SM[c * 128 + mo];
      int n = nl0 + c, hh = n >> 6, d = n & 63;
      int m = m0 + mo, b = m >> 11, key = m & 2047;
      *(bf16x8*)&Vtp[(size_t)((b*12 + hh)*64 + d) * 2048 + key] = v;
    }
  }
}

// ---------------- proj GEMM: 64x64 tile, grid 64x12 = 768 blocks (3.0/CU) ----------------
__global__ __launch_bounds__(256) void k_gemm64(const u16* __restrict__ A, const u16* __restrict__ Bt,
                                                float* __restrict__ Co){
  __shared__ __align__(16) u16 SM[8192];
  u16* Al = SM; u16* Bl = SM + 4096;
  const int tid = threadIdx.x;
  const int w = tid >> 6, l = tid & 63;
  const int m0 = blockIdx.x * 64, n0 = blockIdx.y * 64;
  const int wm = (w >> 1) * 32, wn = (w & 1) * 32;
  const int lg = l >> 4, lr = l & 15;
  f32x4 acc[2][2] = {};
  const u16* asrc = A  + (size_t)(m0 + w*16 + (l >> 3)) * 768 + (l & 7) * 8;
  const u16* bsrc = Bt + (size_t)(n0 + w*16 + (l >> 3)) * 768 + (l & 7) * 8;
  for (int k0 = 0; k0 < 768; k0 += 64){
#pragma unroll
    for (int i = 0; i < 2; ++i){
      GLD16(asrc + (size_t)(i*8)*768 + k0, &Al[(w*16 + i*8) * 64]);
      GLD16(bsrc + (size_t)(i*8)*768 + k0, &Bl[(w*16 + i*8) * 64]);
    }
    __syncthreads();
    bf16x8 af[2][2], bfr[2][2];
#pragma unroll
    for (int mf = 0; mf < 2; ++mf)
#pragma unroll
      for (int ks = 0; ks < 2; ++ks){
        af[mf][ks]  = *(const bf16x8*)&Al[(wm + mf*16 + lr) * 64 + ks*32 + lg*8];
        bfr[mf][ks] = *(const bf16x8*)&Bl[(wn + mf*16 + lr) * 64 + ks*32 + lg*8];
      }
#pragma unroll
    for (int ks = 0; ks < 2; ++ks)
#pragma unroll
      for (int mf = 0; mf < 2; ++mf)
#pragma unroll
        for (int nf = 0; nf < 2; ++nf)
          acc[mf][nf] = __builtin_amdgcn_mfma_f32_16x16x32_bf16(af[mf][ks], bfr[nf][ks], acc[mf][nf], 0, 0, 0);
    __syncthreads();
  }
#pragma unroll
  for (int mf = 0; mf < 2; ++mf)
#pragma unroll
    for (int nf = 0; nf < 2; ++nf)
#pragma unroll
      for (int r = 0; r < 4; ++r)
        Co[(size_t)(m0 + wm + mf*16 + lg*4 + r) * 768 + n0 + wn + nf*16 + lr] = acc[mf][nf][r];
}

// ---------------- flash attention: 32x32 swapped-QK, in-register P, 2 waves x 32 q ----------------
// Fragment maps (gfx950): A row / B col = lane&31, k-slot = (lane>>5, j) (consistent across both
// operands -> any k-bijection cancels). C/D: col = lane&31, row = (reg&3) + 8*(reg>>2) + 4*(lane>>5).
// Swapped S^T = mfma(K, Q): lane's 32 S-values all belong to q = lane&31 (key halves split by lane^32).
__global__ __launch_bounds__(128) void k_attn(const u16* __restrict__ Qp, const u16* __restrict__ Kp,
                                              const u16* __restrict__ Vtp, u16* __restrict__ AO){
  __shared__ __align__(16) u16 Kl[2][64 * 64];   // [key][d] linear 128B rows (T21 swizzled contents)
  __shared__ __align__(16) u16 Vl[2][64 * 64];   // [d][key]
  const int tid = threadIdx.x, w = tid >> 6, l = tid & 63;
  const int q31 = l & 31, hl = l >> 5;
  const int sw7 = l & 7;                          // read-side XOR key (row&7 == l&7 for row=(l&31)+32t)
  const int qt = blockIdx.x, bh = blockIdx.y;
  const int b = bh / 12, hh = bh - b * 12;
  const size_t base = (size_t)bh * (2048 * 64);
  const u16* Qg = Qp + base; const u16* Kg = Kp + base; const u16* Vg = Vtp + base;
  const int q0w = qt * 64 + w * 32;

  // Q B-fragments: q = q31, d = 16*ch + 8*hl + j
  bf16x8 qf[4];
#pragma unroll
  for (int ch = 0; ch < 4; ++ch)
    qf[ch] = *(const bf16x8*)&Qg[(size_t)(q0w + q31) * 64 + 16*ch + 8*hl];

  f32x16 oacc0 = {}, oacc1 = {};
  float m_r = -3e38f, l_part = 0.f;

  // staging: 128 threads, 4 rounds x 16 rows; lane -> row sub r8, pre-swizzled col (T21)
  const int r8  = l >> 3;
  const int csw = ((l & 7) ^ r8) << 3;
  const u16* kb = Kg + (size_t)(w*8 + r8) * 64 + csw;
  const u16* vbg = Vg + ((size_t)(w*8 + r8) << 11) + csw;

#pragma unroll
  for (int rr = 0; rr < 4; ++rr){
    GLD16(kb + (size_t)(rr*16) * 64,   &Kl[0][(rr*16 + w*8) * 64]);
    GLD16(vbg + (size_t)(rr*16) * 2048, &Vl[0][(rr*16 + w*8) * 64]);
  }
  __syncthreads();
  int c = 0;

  for (int k0 = 0; k0 < 2048; k0 += 64){
    if (k0 + 64 < 2048){
      int kn = k0 + 64, nb = c ^ 1;
#pragma unroll
      for (int rr = 0; rr < 4; ++rr){
        GLD16(kb + (size_t)(kn + rr*16) * 64,    &Kl[nb][(rr*16 + w*8) * 64]);
        GLD16(vbg + (size_t)(rr*16) * 2048 + kn, &Vl[nb][(rr*16 + w*8) * 64]);
      }
    }
    const u16* Kc = &Kl[c][0];
    const u16* Vc = &Vl[c][0];

    // QK^T swapped: s0 = keys 0..31, s1 = keys 32..63 (C rows), q = q31 (C col)
    f32x16 s0 = {}, s1 = {};
    __builtin_amdgcn_s_setprio(1);
#pragma unroll
    for (int ch = 0; ch < 4; ++ch){
      int co = ((2*ch + hl) ^ sw7) << 3;
      bf16x8 ka0 = *(const bf16x8*)&Kc[(q31     ) * 64 + co];
      bf16x8 ka1 = *(const bf16x8*)&Kc[(q31 + 32) * 64 + co];
      s0 = __builtin_amdgcn_mfma_f32_32x32x16_bf16(ka0, qf[ch], s0, 0, 0, 0);
      s1 = __builtin_amdgcn_mfma_f32_32x32x16_bf16(ka1, qf[ch], s1, 0, 0, 0);
    }
    __builtin_amdgcn_s_setprio(0);

    // lane-local max over this lane's 32 scores
    float m8[8];
#pragma unroll
    for (int i = 0; i < 8; ++i)
      m8[i] = fmaxf(fmaxf(s0[i], s0[i+8]), fmaxf(s1[i], s1[i+8]));
    float a0 = fmaxf(fmaxf(m8[0], m8[1]), m8[2]);
    float a1 = fmaxf(fmaxf(m8[3], m8[4]), m8[5]);
    float lm = fmaxf(fmaxf(a0, a1), fmaxf(m8[6], m8[7]));

    if (!__all(lm <= m_r + 8.0f)){
      float mq = fmaxf(lm, __shfl_xor(lm, 32));   // true tile max for q=q31
      float nm = fmaxf(m_r, mq);
      float fac = exp2f(m_r - nm);
      m_r = nm;
      l_part *= fac;
#pragma unroll
      for (int reg = 0; reg < 16; ++reg){
        float fr = __shfl(fac, (reg & 3) + 8*(reg >> 2) + 4*hl);
        oacc0[reg] *= fr; oacc1[reg] *= fr;
      }
    }

    // P = exp2(S - m) in place; partial row-sum
#pragma unroll
    for (int i = 0; i < 16; ++i){
      s0[i] = __builtin_exp2f(s0[i] - m_r);
      s1[i] = __builtin_exp2f(s1[i] - m_r);
    }
    float ssum = 0.f;
#pragma unroll
    for (int i = 0; i < 8; ++i) ssum += (s0[i] + s0[i+8]) + (s1[i] + s1[i+8]);
    l_part += ssum;

    // P -> A-fragments: frag ch slot (hl,j) must hold P[q=q31][key = 16ch + 8hl + j].
    // C-reg key map: key(reg,hl) = (reg&3) + 8*(reg>>2) + 4hl (local to s0/s1 32-key half).
    // Lane keeps quad rk = (ch&1)*8 + 4hl (keys 16ch+8hl .. +3 of its own j-half's first 4... see:)
    //   hl=0: kept = keys L..L+3 (j 0-3), recv = partner quad rs -> keys L+4..L+7 (j 4-7)
    //   hl=1: kept = keys L+12..L+15 (j 4-7), recv = partner quad rs -> keys L+8..L+11 (j 0-3)
    // BUGFIX (r6): the shfl must carry the OTHER quad (rs = (ch&1)*8 + 4*(1-hl)), not the kept one.
    bf16x8 pa[4];
#pragma unroll
    for (int ch = 0; ch < 4; ++ch){
      const f32x16& st = (ch < 2) ? s0 : s1;
      int rk = (ch & 1) * 8 + 4 * hl;        // kept quad (own j-half)
      int rs = (ch & 1) * 8 + 4 * (1 - hl);  // sent quad (what the partner needs)
      uint32_t wk0 = pkrhu(st[rk],     st[rk + 1]);
      uint32_t wk1 = pkrhu(st[rk + 2], st[rk + 3]);
      uint32_t ws0 = pkrhu(st[rs],     st[rs + 1]);
      uint32_t ws1 = pkrhu(st[rs + 2], st[rs + 3]);
      uint32_t wr0 = __shfl_xor((int)ws0, 32);
      uint32_t wr1 = __shfl_xor((int)ws1, 32);
      union { uint32_t u[4]; bf16x8 v; } fr;
      fr.u[0] = hl ? wr0 : wk0;
      fr.u[1] = hl ? wr1 : wk1;
      fr.u[2] = hl ? wk0 : wr0;
      fr.u[3] = hl ? wk1 : wr1;
      pa[ch] = fr.v;
    }

    // PV: out[q][d] ; A = P (row=q31=q), B = V^T slots (hl,j) = key 16ch+8hl+j, col d
    __builtin_amdgcn_s_setprio(1);
#pragma unroll
    for (int ch = 0; ch < 4; ++ch){
      int co = ((2*ch + hl) ^ sw7) << 3;
      bf16x8 vb0 = *(const bf16x8*)&Vc[(q31     ) * 64 + co];
      bf16x8 vb1 = *(const bf16x8*)&Vc[(q31 + 32) * 64 + co];
      oacc0 = __builtin_amdgcn_mfma_f32_32x32x16_bf16(pa[ch], vb0, oacc0, 0, 0, 0);
      oacc1 = __builtin_amdgcn_mfma_f32_32x32x16_bf16(pa[ch], vb1, oacc1, 0, 0, 0);
    }
    __builtin_amdgcn_s_setprio(0);

    __syncthreads();   // drains vmcnt -> buf c^1 published
    c ^= 1;
  }

  // normalize + store: oacc row q = (reg&3)+8*(reg>>2)+4hl, col d = q31 (+32)
  float lt = l_part + __shfl_xor(l_part, 32);
  float inv = 1.0f / lt;                          // for q = q31
#pragma unroll
  for (int reg = 0; reg < 16; ++reg){
    int qr = (reg & 3) + 8*(reg >> 2) + 4*hl;
    float ir = __shfl(inv, qr);
    size_t m = (size_t)((b << 11) + q0w + qr) * 768 + hh*64;
    AO[m + q31]      = f2b(oacc0[reg] * ir);
    AO[m + 32 + q31] = f2b(oacc1[reg] * ir);
  }
}

extern "C" void kernel_launch(void* const* d_in, const int* in_sizes, int n_in,
                              void* d_out, int out_size, void* d_ws, size_t ws_size,
                              hipStream_t stream){
  const float* x      = (const float*)d_in[0];
  const float* w_qkv  = (const float*)d_in[1];
  const float* w_proj = (const float*)d_in[2];
  float* out = (float*)d_out;
  char* ws = (char*)d_ws;
  u16* Xb     = (u16*)(ws + 0);
  u16* WqkvT  = (u16*)(ws + 6291456);
  u16* WprojT = (u16*)(ws + 9830400);
  u16* Qp     = (u16*)(ws + 11010048);
  u16* Kp     = (u16*)(ws + 17301504);
  u16* Vtp    = (u16*)(ws + 23592960);
  u16* AO     = (u16*)(ws + 29884416);

  k_cast<<<1536, 256, 0, stream>>>(x, Xb, 393216);
  k_tcast<<<dim3(72, 24), dim3(32, 8), 0, stream>>>(w_qkv, WqkvT, 768, 2304);
  k_tcast<<<dim3(24, 24), dim3(32, 8), 0, stream>>>(w_proj, WprojT, 768, 768);
  k_gemmqkv<<<dim3(32, 24), 256, 0, stream>>>(Xb, WqkvT, Qp, Kp, Vtp);
  k_attn<<<dim3(32, 24), 128, 0, stream>>>(Qp, Kp, Vtp, AO);
  k_gemm64<<<dim3(64, 12), 256, 0, stream>>>(AO, WprojT, out);
}

// Round 9
// 134.105 us; speedup vs baseline: 2.1592x; 2.1592x over previous
//
#include <hip/hip_runtime.h>
#include <hip/hip_bf16.h>
#include <stdint.h>

typedef uint16_t u16;
typedef __attribute__((ext_vector_type(4))) float f32x4;
typedef __attribute__((ext_vector_type(16))) float f32x16;
typedef __attribute__((ext_vector_type(8))) short bf16x8;

#define LOG2E 1.4426950408889634f

static __device__ __forceinline__ u16 f2b(float x){
  union { float f; uint32_t u; } a; a.f = x;
  uint32_t r = a.u + 0x7FFFu + ((a.u >> 16) & 1u);
  return (u16)(r >> 16);
}

// pack two f32 -> two bf16 (round-half-up) in 3 VALU: add, add, v_perm_b32
static __device__ __forceinline__ uint32_t pkrhu(float lo, float hi){
  union { float f; uint32_t u; } a, b; a.f = lo; b.f = hi;
  return __builtin_amdgcn_perm(b.u + 0x8000u, a.u + 0x8000u, 0x07060302u);
}

#define GLD16(g, l) __builtin_amdgcn_global_load_lds((const __attribute__((address_space(1))) void*)(g), (__attribute__((address_space(3))) void*)(l), 16, 0, 0)

// ---------------- cast x: fp32 -> bf16 (8 elems/thread) ----------------
__global__ __launch_bounds__(256) void k_cast(const float* __restrict__ in, u16* __restrict__ out, int n8){
  int i = blockIdx.x * 256 + threadIdx.x;
  if (i >= n8) return;
  const f32x4* p = (const f32x4*)(in + (size_t)i * 8);
  f32x4 a = p[0], b = p[1];
  u16 h[8];
#pragma unroll
  for (int j = 0; j < 4; ++j){ h[j] = f2b(a[j]); h[4+j] = f2b(b[j]); }
  *(bf16x8*)(out + (size_t)i * 8) = *(const bf16x8*)h;
}

// ---------------- transpose-cast: W[R][C] fp32 -> Wt[C][R] bf16 ----------------
__global__ void k_tcast(const float* __restrict__ in, u16* __restrict__ out, int R, int C){
  __shared__ float t[32][33];
  int c0 = blockIdx.x * 32, r0 = blockIdx.y * 32;
  int tx = threadIdx.x, ty = threadIdx.y; // 32 x 8
#pragma unroll
  for (int i = 0; i < 32; i += 8) t[ty + i][tx] = in[(size_t)(r0 + ty + i) * C + c0 + tx];
  __syncthreads();
#pragma unroll
  for (int i = 0; i < 32; i += 8) out[(size_t)(c0 + ty + i) * R + r0 + tx] = f2b(t[tx][ty + i]);
}

// ---------------- QKV GEMM: 128x96 tile, grid 32x24 = 768 blocks (3.0/CU) ----------------
__global__ __launch_bounds__(256) void k_gemmqkv(const u16* __restrict__ A, const u16* __restrict__ Bt,
                                                 u16* __restrict__ Qp, u16* __restrict__ Kp, u16* __restrict__ Vtp){
  __shared__ __align__(16) u16 SM[14336];
  u16* Al = SM; u16* Bl = SM + 8192;
  const int tid = threadIdx.x;
  const int w = tid >> 6, l = tid & 63;
  const int m0 = blockIdx.x * 128, n0 = blockIdx.y * 96;
  const int wm = (w >> 1) * 64, wn = (w & 1) * 48;
  const int lg = l >> 4, lr = l & 15;
  f32x4 acc[4][3] = {};
  const u16* asrc = A  + (size_t)(m0 + w*32 + (l >> 3)) * 768 + (l & 7) * 8;
  const u16* bsrc = Bt + (size_t)(n0 + w*24 + (l >> 3)) * 768 + (l & 7) * 8;
  for (int k0 = 0; k0 < 768; k0 += 64){
#pragma unroll
    for (int i = 0; i < 4; ++i)
      GLD16(asrc + (size_t)(i*8)*768 + k0, &Al[(w*32 + i*8) * 64]);
#pragma unroll
    for (int i = 0; i < 3; ++i)
      GLD16(bsrc + (size_t)(i*8)*768 + k0, &Bl[(w*24 + i*8) * 64]);
    __syncthreads();
    bf16x8 af[4][2], bfr[3][2];
#pragma unroll
    for (int mf = 0; mf < 4; ++mf)
#pragma unroll
      for (int ks = 0; ks < 2; ++ks)
        af[mf][ks] = *(const bf16x8*)&Al[(wm + mf*16 + lr) * 64 + ks*32 + lg*8];
#pragma unroll
    for (int nf = 0; nf < 3; ++nf)
#pragma unroll
      for (int ks = 0; ks < 2; ++ks)
        bfr[nf][ks] = *(const bf16x8*)&Bl[(wn + nf*16 + lr) * 64 + ks*32 + lg*8];
#pragma unroll
    for (int ks = 0; ks < 2; ++ks)
#pragma unroll
      for (int mf = 0; mf < 4; ++mf)
#pragma unroll
        for (int nf = 0; nf < 3; ++nf)
          acc[mf][nf] = __builtin_amdgcn_mfma_f32_16x16x32_bf16(af[mf][ks], bfr[nf][ks], acc[mf][nf], 0, 0, 0);
    __syncthreads();
  }

  const int which = n0 / 768;
  const int nl0 = n0 - which * 768;
  if (which < 2){
    u16* dst = (which == 0) ? Qp : Kp;
    const float sc = (which == 0) ? 0.125f * LOG2E : 1.0f;
#pragma unroll
    for (int mf = 0; mf < 4; ++mf)
#pragma unroll
      for (int nf = 0; nf < 3; ++nf)
#pragma unroll
        for (int r = 0; r < 4; ++r){
          int m = m0 + wm + mf*16 + lg*4 + r;
          int n = nl0 + wn + nf*16 + lr;
          int b = m >> 11, row = m & 2047, hh = n >> 6, d = n & 63;
          dst[(size_t)((b*12 + hh)*2048 + row) * 64 + d] = f2b(acc[mf][nf][r] * sc);
        }
  } else {
#pragma unroll
    for (int mf = 0; mf < 4; ++mf)
#pragma unroll
      for (int nf = 0; nf < 3; ++nf)
#pragma unroll
        for (int r = 0; r < 4; ++r){
          int mrow = wm + mf*16 + lg*4 + r;
          int c    = wn + nf*16 + lr;
          SM[c * 128 + mrow] = f2b(acc[mf][nf][r]);
        }
    __syncthreads();
#pragma unroll
    for (int rr = 0; rr < 6; ++rr){
      int c  = rr*16 + (tid >> 4);
      int mo = (tid & 15) * 8;
      bf16x8 v = *(const bf16x8*)&SM[c * 128 + mo];
      int n = nl0 + c, hh = n >> 6, d = n & 63;
      int m = m0 + mo, b = m >> 11, key = m & 2047;
      *(bf16x8*)&Vtp[(size_t)((b*12 + hh)*64 + d) * 2048 + key] = v;
    }
  }
}

// ---------------- proj GEMM: 64x64 tile, grid 64x12 = 768 blocks (3.0/CU) ----------------
__global__ __launch_bounds__(256) void k_gemm64(const u16* __restrict__ A, const u16* __restrict__ Bt,
                                                float* __restrict__ Co){
  __shared__ __align__(16) u16 SM[8192];
  u16* Al = SM; u16* Bl = SM + 4096;
  const int tid = threadIdx.x;
  const int w = tid >> 6, l = tid & 63;
  const int m0 = blockIdx.x * 64, n0 = blockIdx.y * 64;
  const int wm = (w >> 1) * 32, wn = (w & 1) * 32;
  const int lg = l >> 4, lr = l & 15;
  f32x4 acc[2][2] = {};
  const u16* asrc = A  + (size_t)(m0 + w*16 + (l >> 3)) * 768 + (l & 7) * 8;
  const u16* bsrc = Bt + (size_t)(n0 + w*16 + (l >> 3)) * 768 + (l & 7) * 8;
  for (int k0 = 0; k0 < 768; k0 += 64){
#pragma unroll
    for (int i = 0; i < 2; ++i){
      GLD16(asrc + (size_t)(i*8)*768 + k0, &Al[(w*16 + i*8) * 64]);
      GLD16(bsrc + (size_t)(i*8)*768 + k0, &Bl[(w*16 + i*8) * 64]);
    }
    __syncthreads();
    bf16x8 af[2][2], bfr[2][2];
#pragma unroll
    for (int mf = 0; mf < 2; ++mf)
#pragma unroll
      for (int ks = 0; ks < 2; ++ks){
        af[mf][ks]  = *(const bf16x8*)&Al[(wm + mf*16 + lr) * 64 + ks*32 + lg*8];
        bfr[mf][ks] = *(const bf16x8*)&Bl[(wn + mf*16 + lr) * 64 + ks*32 + lg*8];
      }
#pragma unroll
    for (int ks = 0; ks < 2; ++ks)
#pragma unroll
      for (int mf = 0; mf < 2; ++mf)
#pragma unroll
        for (int nf = 0; nf < 2; ++nf)
          acc[mf][nf] = __builtin_amdgcn_mfma_f32_16x16x32_bf16(af[mf][ks], bfr[nf][ks], acc[mf][nf], 0, 0, 0);  // BUGFIX r9: bfr[nf] (was bfr[mf])
    __syncthreads();
  }
#pragma unroll
  for (int mf = 0; mf < 2; ++mf)
#pragma unroll
    for (int nf = 0; nf < 2; ++nf)
#pragma unroll
      for (int r = 0; r < 4; ++r)
        Co[(size_t)(m0 + wm + mf*16 + lg*4 + r) * 768 + n0 + wn + nf*16 + lr] = acc[mf][nf][r];
}

// ---------------- flash attention: 32x32 swapped-QK, in-register P, 2 waves x 32 q ----------------
// Fragment maps (gfx950): A row / B col = lane&31, k-slot = (lane>>5, j) (consistent across both
// operands -> any k-bijection cancels). C/D: col = lane&31, row = (reg&3) + 8*(reg>>2) + 4*(lane>>5).
// Swapped S^T = mfma(K, Q): lane's 32 S-values all belong to q = lane&31 (key halves split by lane^32).
__global__ __launch_bounds__(128) void k_attn(const u16* __restrict__ Qp, const u16* __restrict__ Kp,
                                              const u16* __restrict__ Vtp, u16* __restrict__ AO){
  __shared__ __align__(16) u16 Kl[2][64 * 64];   // [key][d] linear 128B rows (T21 swizzled contents)
  __shared__ __align__(16) u16 Vl[2][64 * 64];   // [d][key]
  const int tid = threadIdx.x, w = tid >> 6, l = tid & 63;
  const int q31 = l & 31, hl = l >> 5;
  const int sw7 = l & 7;                          // read-side XOR key (row&7 == l&7 for row=(l&31)+32t)
  const int qt = blockIdx.x, bh = blockIdx.y;
  const int b = bh / 12, hh = bh - b * 12;
  const size_t base = (size_t)bh * (2048 * 64);
  const u16* Qg = Qp + base; const u16* Kg = Kp + base; const u16* Vg = Vtp + base;
  const int q0w = qt * 64 + w * 32;

  // Q B-fragments: q = q31, d = 16*ch + 8*hl + j
  bf16x8 qf[4];
#pragma unroll
  for (int ch = 0; ch < 4; ++ch)
    qf[ch] = *(const bf16x8*)&Qg[(size_t)(q0w + q31) * 64 + 16*ch + 8*hl];

  f32x16 oacc0 = {}, oacc1 = {};
  float m_r = -3e38f, l_part = 0.f;

  // staging: 128 threads, 4 rounds x 16 rows; lane -> row sub r8, pre-swizzled col (T21)
  const int r8  = l >> 3;
  const int csw = ((l & 7) ^ r8) << 3;
  const u16* kb = Kg + (size_t)(w*8 + r8) * 64 + csw;
  const u16* vbg = Vg + ((size_t)(w*8 + r8) << 11) + csw;

#pragma unroll
  for (int rr = 0; rr < 4; ++rr){
    GLD16(kb + (size_t)(rr*16) * 64,   &Kl[0][(rr*16 + w*8) * 64]);
    GLD16(vbg + (size_t)(rr*16) * 2048, &Vl[0][(rr*16 + w*8) * 64]);
  }
  __syncthreads();
  int c = 0;

  for (int k0 = 0; k0 < 2048; k0 += 64){
    if (k0 + 64 < 2048){
      int kn = k0 + 64, nb = c ^ 1;
#pragma unroll
      for (int rr = 0; rr < 4; ++rr){
        GLD16(kb + (size_t)(kn + rr*16) * 64,    &Kl[nb][(rr*16 + w*8) * 64]);
        GLD16(vbg + (size_t)(rr*16) * 2048 + kn, &Vl[nb][(rr*16 + w*8) * 64]);
      }
    }
    const u16* Kc = &Kl[c][0];
    const u16* Vc = &Vl[c][0];

    // QK^T swapped: s0 = keys 0..31, s1 = keys 32..63 (C rows), q = q31 (C col)
    f32x16 s0 = {}, s1 = {};
    __builtin_amdgcn_s_setprio(1);
#pragma unroll
    for (int ch = 0; ch < 4; ++ch){
      int co = ((2*ch + hl) ^ sw7) << 3;
      bf16x8 ka0 = *(const bf16x8*)&Kc[(q31     ) * 64 + co];
      bf16x8 ka1 = *(const bf16x8*)&Kc[(q31 + 32) * 64 + co];
      s0 = __builtin_amdgcn_mfma_f32_32x32x16_bf16(ka0, qf[ch], s0, 0, 0, 0);
      s1 = __builtin_amdgcn_mfma_f32_32x32x16_bf16(ka1, qf[ch], s1, 0, 0, 0);
    }
    __builtin_amdgcn_s_setprio(0);

    // lane-local max over this lane's 32 scores
    float m8[8];
#pragma unroll
    for (int i = 0; i < 8; ++i)
      m8[i] = fmaxf(fmaxf(s0[i], s0[i+8]), fmaxf(s1[i], s1[i+8]));
    float a0m = fmaxf(fmaxf(m8[0], m8[1]), m8[2]);
    float a1m = fmaxf(fmaxf(m8[3], m8[4]), m8[5]);
    float lm = fmaxf(fmaxf(a0m, a1m), fmaxf(m8[6], m8[7]));

    if (!__all(lm <= m_r + 8.0f)){
      float mq = fmaxf(lm, __shfl_xor(lm, 32));   // true tile max for q=q31
      float nm = fmaxf(m_r, mq);
      float fac = exp2f(m_r - nm);
      m_r = nm;
      l_part *= fac;
#pragma unroll
      for (int reg = 0; reg < 16; ++reg){
        float fr = __shfl(fac, (reg & 3) + 8*(reg >> 2) + 4*hl);
        oacc0[reg] *= fr; oacc1[reg] *= fr;
      }
    }

    // P = exp2(S - m) in place; partial row-sum
#pragma unroll
    for (int i = 0; i < 16; ++i){
      s0[i] = __builtin_exp2f(s0[i] - m_r);
      s1[i] = __builtin_exp2f(s1[i] - m_r);
    }
    float ssum = 0.f;
#pragma unroll
    for (int i = 0; i < 8; ++i) ssum += (s0[i] + s0[i+8]) + (s1[i] + s1[i+8]);
    l_part += ssum;

    // P -> A-fragments. Frag ch slot (hl,j) holds P[q=q31][key = 16ch + 8hl + j].
    // All ext_vector indices compile-time (rule #20); hl-routing via value selects.
    //   hl=0: kept=a (j0-3), sent=b; fr={a, recv}   hl=1: kept=b (j4-7), sent=a; fr={recv, b}
    bf16x8 pa[4];
#pragma unroll
    for (int ch = 0; ch < 4; ++ch){
      const f32x16& st = (ch < 2) ? s0 : s1;
      const int qb = (ch & 1) * 8;
      uint32_t a0 = pkrhu(st[qb + 0], st[qb + 1]);
      uint32_t a1 = pkrhu(st[qb + 2], st[qb + 3]);
      uint32_t b0 = pkrhu(st[qb + 4], st[qb + 5]);
      uint32_t b1 = pkrhu(st[qb + 6], st[qb + 7]);
      uint32_t ws0 = hl ? a0 : b0, ws1 = hl ? a1 : b1;   // sent quad
      uint32_t wk0 = hl ? b0 : a0, wk1 = hl ? b1 : a1;   // kept quad
      uint32_t wr0 = __shfl_xor((int)ws0, 32);
      uint32_t wr1 = __shfl_xor((int)ws1, 32);
      union { uint32_t u[4]; bf16x8 v; } fr;
      fr.u[0] = hl ? wr0 : wk0;
      fr.u[1] = hl ? wr1 : wk1;
      fr.u[2] = hl ? wk0 : wr0;
      fr.u[3] = hl ? wk1 : wr1;
      pa[ch] = fr.v;
    }

    // PV: out[q][d] ; A = P (row=q31=q), B = V^T slots (hl,j) = key 16ch+8hl+j, col d
    __builtin_amdgcn_s_setprio(1);
#pragma unroll
    for (int ch = 0; ch < 4; ++ch){
      int co = ((2*ch + hl) ^ sw7) << 3;
      bf16x8 vb0 = *(const bf16x8*)&Vc[(q31     ) * 64 + co];
      bf16x8 vb1 = *(const bf16x8*)&Vc[(q31 + 32) * 64 + co];
      oacc0 = __builtin_amdgcn_mfma_f32_32x32x16_bf16(pa[ch], vb0, oacc0, 0, 0, 0);
      oacc1 = __builtin_amdgcn_mfma_f32_32x32x16_bf16(pa[ch], vb1, oacc1, 0, 0, 0);
    }
    __builtin_amdgcn_s_setprio(0);

    __syncthreads();   // drains vmcnt -> buf c^1 published
    c ^= 1;
  }

  // normalize + store: oacc row q = (reg&3)+8*(reg>>2)+4hl, col d = q31 (+32)
  float lt = l_part + __shfl_xor(l_part, 32);
  float inv = 1.0f / lt;                          // for q = q31
#pragma unroll
  for (int reg = 0; reg < 16; ++reg){
    int qr = (reg & 3) + 8*(reg >> 2) + 4*hl;
    float ir = __shfl(inv, qr);
    size_t m = (size_t)((b << 11) + q0w + qr) * 768 + hh*64;
    AO[m + q31]      = f2b(oacc0[reg] * ir);
    AO[m + 32 + q31] = f2b(oacc1[reg] * ir);
  }
}

extern "C" void kernel_launch(void* const* d_in, const int* in_sizes, int n_in,
                              void* d_out, int out_size, void* d_ws, size_t ws_size,
                              hipStream_t stream){
  const float* x      = (const float*)d_in[0];
  const float* w_qkv  = (const float*)d_in[1];
  const float* w_proj = (const float*)d_in[2];
  float* out = (float*)d_out;
  char* ws = (char*)d_ws;
  u16* Xb     = (u16*)(ws + 0);
  u16* WqkvT  = (u16*)(ws + 6291456);
  u16* WprojT = (u16*)(ws + 9830400);
  u16* Qp     = (u16*)(ws + 11010048);
  u16* Kp     = (u16*)(ws + 17301504);
  u16* Vtp    = (u16*)(ws + 23592960);
  u16* AO     = (u16*)(ws + 29884416);

  k_cast<<<1536, 256, 0, stream>>>(x, Xb, 393216);
  k_tcast<<<dim3(72, 24), dim3(32, 8), 0, stream>>>(w_qkv, WqkvT, 768, 2304);
  k_tcast<<<dim3(24, 24), dim3(32, 8), 0, stream>>>(w_proj, WprojT, 768, 768);
  k_gemmqkv<<<dim3(32, 24), 256, 0, stream>>>(Xb, WqkvT, Qp, Kp, Vtp);
  k_attn<<<dim3(32, 24), 128, 0, stream>>>(Qp, Kp, Vtp, AO);
  k_gemm64<<<dim3(64, 12), 256, 0, stream>>>(AO, WprojT, out);
}